// Round 2
// baseline (438.227 us; speedup 1.0000x reference)
//
#include <hip/hip_runtime.h>

#define PAST 12
#define FUTURE 12
#define NB 64
#define NL 256
#define ND 512
#define NW 244  // NL - PAST

typedef unsigned short ushort_t;
typedef __attribute__((ext_vector_type(8))) short short8;
typedef __attribute__((ext_vector_type(4))) float floatx4;

__device__ inline float bf2f(ushort_t u) {
    return __uint_as_float(((unsigned int)u) << 16);
}
__device__ inline unsigned int f2bf(float x) {
    unsigned int u = __float_as_uint(x);
    return (u + 0x7fffu + ((u >> 16) & 1u)) >> 16;  // RNE
}

// ---------------- Stage 0a: inp fp32 -> bf16 ----------------
__global__ __launch_bounds__(256) void convert_inp(
    const float* __restrict__ in, ushort_t* __restrict__ out)
{
    const int i = (blockIdx.x * 256 + threadIdx.x) * 4;  // total 16,777,216 elems, /4 exact
    const float4 v = *(const float4*)(in + i);
    unsigned int lo = f2bf(v.x) | (f2bf(v.y) << 16);
    unsigned int hi = f2bf(v.z) | (f2bf(v.w) << 16);
    *(uint2*)(out + i) = make_uint2(lo, hi);
}

// ---------------- Stage 0b: W_s fp32 -> bf16, and S[e] = sum_d W_s[e][d] ----------------
__global__ __launch_bounds__(256) void prep_ws(
    const float* __restrict__ Ws, ushort_t* __restrict__ Wsb, float* __restrict__ S)
{
    const int row = blockIdx.x;       // 0..511
    const int t = threadIdx.x;        // 0..255
    const float* r = Ws + (size_t)row * ND + t * 2;
    const float2 v = *(const float2*)r;
    *(unsigned int*)(Wsb + (size_t)row * ND + t * 2) = f2bf(v.x) | (f2bf(v.y) << 16);
    float s = v.x + v.y;
#pragma unroll
    for (int o = 32; o > 0; o >>= 1) s += __shfl_down(s, o);
    __shared__ float red[4];
    if ((t & 63) == 0) red[t >> 6] = s;
    __syncthreads();
    if (t == 0) S[row] = red[0] + red[1] + red[2] + red[3];
}

// ---------------- Stage 1: y = inp @ W_s^T  (NT bf16 MFMA GEMM) ----------------
// A: inp_bf16 [M=16384, K=512] row-major
// B: Ws_bf16  [N=512,   K=512] row-major (row e, col d)  -> B^T layout
// Y: [M, N] bf16
#define BM 128
#define BN 128
#define BK 32

__global__ __launch_bounds__(256) void gemm_spatial(
    const ushort_t* __restrict__ A,
    const ushort_t* __restrict__ Bm,
    ushort_t* __restrict__ Y)
{
    __shared__ ushort_t As[BM * BK];  // row-major [128][32], no pad (global_load_lds)
    __shared__ ushort_t Bs[BN * BK];

    const int tid  = threadIdx.x;      // 0..255
    const int wave = tid >> 6;         // 0..3
    const int lane = tid & 63;
    const int m0 = blockIdx.y * BM;
    const int n0 = blockIdx.x * BN;
    const int wm = (wave >> 1) * 64;
    const int wn = (wave & 1) * 64;

    floatx4 acc[4][4] = {};

    const int row_a = tid >> 2;        // staging: 4 lanes per 32-elem row
    const int ch_a  = (tid & 3) * 8;   // 8 bf16 = 16B per lane

    for (int k0 = 0; k0 < ND; k0 += BK) {
        __syncthreads();
#pragma unroll
        for (int r = 0; r < 2; ++r) {
            const ushort_t* ga = A + (size_t)(m0 + row_a + r * 64) * ND + k0 + ch_a;
            __builtin_amdgcn_global_load_lds(
                (const __attribute__((address_space(1))) unsigned int*)ga,
                (__attribute__((address_space(3))) unsigned int*)(As + (r * 256 + wave * 64) * 8),
                16, 0, 0);
        }
#pragma unroll
        for (int r = 0; r < 2; ++r) {
            const ushort_t* gb = Bm + (size_t)(n0 + row_a + r * 64) * ND + k0 + ch_a;
            __builtin_amdgcn_global_load_lds(
                (const __attribute__((address_space(1))) unsigned int*)gb,
                (__attribute__((address_space(3))) unsigned int*)(Bs + (r * 256 + wave * 64) * 8),
                16, 0, 0);
        }
        __syncthreads();

        const ushort_t* a_base = As + (wm + (lane & 15)) * BK + (lane >> 4) * 8;
        const ushort_t* b_base = Bs + (wn + (lane & 15)) * BK + (lane >> 4) * 8;
        short8 a[4], b[4];
#pragma unroll
        for (int t = 0; t < 4; ++t) {
            a[t] = *(const short8*)(a_base + t * 16 * BK);
            b[t] = *(const short8*)(b_base + t * 16 * BK);
        }
#pragma unroll
        for (int i = 0; i < 4; ++i)
#pragma unroll
            for (int j = 0; j < 4; ++j)
                acc[i][j] = __builtin_amdgcn_mfma_f32_16x16x32_bf16(a[i], b[j], acc[i][j], 0, 0, 0);
    }

    // D layout: col = lane&15 (N), row = (lane>>4)*4 + reg (M)
#pragma unroll
    for (int i = 0; i < 4; ++i) {
        const int m_base = m0 + wm + i * 16 + (lane >> 4) * 4;
#pragma unroll
        for (int j = 0; j < 4; ++j) {
            const int n = n0 + wn + j * 16 + (lane & 15);
#pragma unroll
            for (int r = 0; r < 4; ++r) {
                Y[(size_t)(m_base + r) * ND + n] = (ushort_t)f2bf(acc[i][j][r]);
            }
        }
    }
}

// ---------------- Stage 2: temporal mix + biases (fp32 out) ----------------
// out[b,w,f,e] = sum_p W_t[f,p]*y[b,w+p,e] + b_t[f]*S[e] + b_s[e]
#define TW 8

__global__ __launch_bounds__(256) void temporal_kernel(
    const ushort_t* __restrict__ Y,    // [64*256, 512] bf16
    const float*    __restrict__ Wt,   // [12,12] fp32
    const float*    __restrict__ bt,   // [12] fp32
    const float*    __restrict__ bs,   // [512] fp32
    const float*    __restrict__ S,    // [512] fp32
    float*          __restrict__ Out)  // [64,244,12,512] fp32
{
    __shared__ float wt_s[FUTURE][PAST];
    const int tid = threadIdx.x;       // 0..255
    const int b  = blockIdx.y;
    const int w0 = blockIdx.x * TW;

    if (tid < FUTURE * PAST) {
        wt_s[tid / PAST][tid % PAST] = Wt[tid];
    }
    __syncthreads();

    const int e = tid * 2;             // pair of consecutive e
    const float S0 = S[e], S1 = S[e + 1];
    const float bs0 = bs[e], bs1 = bs[e + 1];
    float bt_f[FUTURE];
#pragma unroll
    for (int f = 0; f < FUTURE; ++f) bt_f[f] = bt[f];

    // sliding window of y rows in registers (bf16 pair -> 2 floats)
    float yw0[TW + PAST - 1], yw1[TW + PAST - 1];
    const ushort_t* ybase = Y + ((size_t)(b * NL + w0)) * ND + e;
#pragma unroll
    for (int i = 0; i < TW + PAST - 1; ++i) {
        if (w0 + i < NL) {
            unsigned int v = *(const unsigned int*)(ybase + (size_t)i * ND);
            yw0[i] = __uint_as_float(v << 16);
            yw1[i] = __uint_as_float(v & 0xffff0000u);
        } else {
            yw0[i] = 0.f; yw1[i] = 0.f;
        }
    }

#pragma unroll
    for (int w = 0; w < TW; ++w) {
        if (w0 + w < NW) {
            float acc0[FUTURE], acc1[FUTURE];
#pragma unroll
            for (int f = 0; f < FUTURE; ++f) {
                acc0[f] = fmaf(bt_f[f], S0, bs0);
                acc1[f] = fmaf(bt_f[f], S1, bs1);
            }
#pragma unroll
            for (int p = 0; p < PAST; ++p) {
                const float v0 = yw0[w + p], v1 = yw1[w + p];
#pragma unroll
                for (int f = 0; f < FUTURE; ++f) {
                    const float c = wt_s[f][p];
                    acc0[f] = fmaf(c, v0, acc0[f]);
                    acc1[f] = fmaf(c, v1, acc1[f]);
                }
            }
            const size_t obase = ((size_t)(b * NW + (w0 + w)) * FUTURE) * ND + e;
#pragma unroll
            for (int f = 0; f < FUTURE; ++f) {
                *(float2*)(Out + obase + (size_t)f * ND) = make_float2(acc0[f], acc1[f]);
            }
        }
    }
}

// ---------------- launch ----------------
extern "C" void kernel_launch(void* const* d_in, const int* in_sizes, int n_in,
                              void* d_out, int out_size, void* d_ws, size_t ws_size,
                              hipStream_t stream) {
    const float* inp = (const float*)d_in[0];  // [64,256,512] fp32
    const float* Wt  = (const float*)d_in[1];  // [12,12]
    const float* bt  = (const float*)d_in[2];  // [12]
    const float* Ws  = (const float*)d_in[3];  // [512,512]
    const float* bs  = (const float*)d_in[4];  // [512]
    float* out = (float*)d_out;

    const size_t n_inp = (size_t)NB * NL * ND;            // 16,777,216
    ushort_t* Y     = (ushort_t*)d_ws;                     // 16.78 MB
    ushort_t* inp_b = (ushort_t*)((char*)d_ws + n_inp * 2);         // +16.78 MB
    ushort_t* Ws_b  = (ushort_t*)((char*)d_ws + n_inp * 4);         // +0.5 MB
    float*    S     = (float*)((char*)d_ws + n_inp * 4 + (size_t)ND * ND * 2);  // +2 KB

    convert_inp<<<dim3(n_inp / 4 / 256), dim3(256), 0, stream>>>(inp, inp_b);
    prep_ws<<<dim3(ND), dim3(256), 0, stream>>>(Ws, Ws_b, S);
    gemm_spatial<<<dim3(ND / BN, (NB * NL) / BM), dim3(256), 0, stream>>>(inp_b, Ws_b, Y);
    temporal_kernel<<<dim3((NW + TW - 1) / TW, NB), dim3(256), 0, stream>>>(Y, Wt, bt, bs, S, out);
}

// Round 3
// 436.860 us; speedup vs baseline: 1.0031x; 1.0031x over previous
//
#include <hip/hip_runtime.h>

#define PAST 12
#define FUTURE 12
#define NB 64
#define NL 256
#define ND 512
#define NW 244  // NL - PAST

typedef unsigned short ushort_t;
typedef __attribute__((ext_vector_type(8))) short short8;
typedef __attribute__((ext_vector_type(4))) float floatx4;

__device__ inline unsigned int f2bf(float x) {
    unsigned int u = __float_as_uint(x);
    return (u + 0x7fffu + ((u >> 16) & 1u)) >> 16;  // RNE
}

// ---------------- Stage 0a: inp fp32 -> bf16 (8 elems/thread) ----------------
__global__ __launch_bounds__(256) void convert_inp(
    const float* __restrict__ in, ushort_t* __restrict__ out)
{
    const int i = (blockIdx.x * 256 + threadIdx.x) * 8;  // 16,777,216 elems, /8 exact
    const float4 v0 = *(const float4*)(in + i);
    const float4 v1 = *(const float4*)(in + i + 4);
    uint4 o;
    o.x = f2bf(v0.x) | (f2bf(v0.y) << 16);
    o.y = f2bf(v0.z) | (f2bf(v0.w) << 16);
    o.z = f2bf(v1.x) | (f2bf(v1.y) << 16);
    o.w = f2bf(v1.z) | (f2bf(v1.w) << 16);
    *(uint4*)(out + i) = o;
}

// ---------------- Stage 0b: W_s fp32 -> bf16, and S[e] = sum_d W_s[e][d] ----------------
__global__ __launch_bounds__(256) void prep_ws(
    const float* __restrict__ Ws, ushort_t* __restrict__ Wsb, float* __restrict__ S)
{
    const int row = blockIdx.x;       // 0..511
    const int t = threadIdx.x;        // 0..255
    const float2 v = *(const float2*)(Ws + (size_t)row * ND + t * 2);
    *(unsigned int*)(Wsb + (size_t)row * ND + t * 2) = f2bf(v.x) | (f2bf(v.y) << 16);
    float s = v.x + v.y;
#pragma unroll
    for (int o = 32; o > 0; o >>= 1) s += __shfl_down(s, o);
    __shared__ float red[4];
    if ((t & 63) == 0) red[t >> 6] = s;
    __syncthreads();
    if (t == 0) S[row] = red[0] + red[1] + red[2] + red[3];
}

// ---------------- Stage 1: y = inp @ W_s^T  (NT bf16 MFMA GEMM) ----------------
#define BM 128
#define BN 128
#define BK 32

__global__ __launch_bounds__(256) void gemm_spatial(
    const ushort_t* __restrict__ A,
    const ushort_t* __restrict__ Bm,
    ushort_t* __restrict__ Y)
{
    __shared__ ushort_t As[BM * BK];
    __shared__ ushort_t Bs[BN * BK];

    const int tid  = threadIdx.x;
    const int wave = tid >> 6;
    const int lane = tid & 63;
    const int m0 = blockIdx.y * BM;
    const int n0 = blockIdx.x * BN;
    const int wm = (wave >> 1) * 64;
    const int wn = (wave & 1) * 64;

    floatx4 acc[4][4] = {};

    const int row_a = tid >> 2;
    const int ch_a  = (tid & 3) * 8;

    for (int k0 = 0; k0 < ND; k0 += BK) {
        __syncthreads();
#pragma unroll
        for (int r = 0; r < 2; ++r) {
            const ushort_t* ga = A + (size_t)(m0 + row_a + r * 64) * ND + k0 + ch_a;
            __builtin_amdgcn_global_load_lds(
                (const __attribute__((address_space(1))) unsigned int*)ga,
                (__attribute__((address_space(3))) unsigned int*)(As + (r * 256 + wave * 64) * 8),
                16, 0, 0);
        }
#pragma unroll
        for (int r = 0; r < 2; ++r) {
            const ushort_t* gb = Bm + (size_t)(n0 + row_a + r * 64) * ND + k0 + ch_a;
            __builtin_amdgcn_global_load_lds(
                (const __attribute__((address_space(1))) unsigned int*)gb,
                (__attribute__((address_space(3))) unsigned int*)(Bs + (r * 256 + wave * 64) * 8),
                16, 0, 0);
        }
        __syncthreads();

        const ushort_t* a_base = As + (wm + (lane & 15)) * BK + (lane >> 4) * 8;
        const ushort_t* b_base = Bs + (wn + (lane & 15)) * BK + (lane >> 4) * 8;
        short8 a[4], b[4];
#pragma unroll
        for (int t = 0; t < 4; ++t) {
            a[t] = *(const short8*)(a_base + t * 16 * BK);
            b[t] = *(const short8*)(b_base + t * 16 * BK);
        }
#pragma unroll
        for (int i = 0; i < 4; ++i)
#pragma unroll
            for (int j = 0; j < 4; ++j)
                acc[i][j] = __builtin_amdgcn_mfma_f32_16x16x32_bf16(a[i], b[j], acc[i][j], 0, 0, 0);
    }

#pragma unroll
    for (int i = 0; i < 4; ++i) {
        const int m_base = m0 + wm + i * 16 + (lane >> 4) * 4;
#pragma unroll
        for (int j = 0; j < 4; ++j) {
            const int n = n0 + wn + j * 16 + (lane & 15);
#pragma unroll
            for (int r = 0; r < 4; ++r) {
                Y[(size_t)(m_base + r) * ND + n] = (ushort_t)f2bf(acc[i][j][r]);
            }
        }
    }
}

// ---------------- Stage 2: temporal mix + biases (fp32 out, float4 stores) ----------------
// out[b,w,f,e] = sum_p W_t[f,p]*y[b,w+p,e] + b_t[f]*S[e] + b_s[e]
// Block: 256 threads = 2 halves of 128. Half h covers w in [w0+4h, w0+4h+3],
// thread owns e-quad eq = (tid&127)*4. Window: 15 rows x 4 floats in VGPRs.
#define WTILE 8

__global__ __launch_bounds__(256) void temporal_kernel(
    const ushort_t* __restrict__ Y,    // [64*256, 512] bf16
    const float*    __restrict__ Wt,   // [12,12] fp32 (wave-uniform -> s_load)
    const float*    __restrict__ bt,   // [12] fp32
    const float*    __restrict__ bs,   // [512] fp32
    const float*    __restrict__ S,    // [512] fp32
    float*          __restrict__ Out)  // [64,244,12,512] fp32
{
    const int tid = threadIdx.x;
    const int b  = blockIdx.y;
    const int w0 = blockIdx.x * WTILE + (tid >> 7) * 4;  // half-block w-base
    const int eq = (tid & 127) * 4;

    const float4 Sv  = *(const float4*)(S + eq);
    const float4 bsv = *(const float4*)(bs + eq);

    // 15-row sliding window, 4 e's per thread, registers only (all indices constant)
    float win[PAST + 3][4];
    const ushort_t* ybase = Y + ((size_t)(b * NL + w0)) * ND + eq;
#pragma unroll
    for (int i = 0; i < PAST + 3; ++i) {
        if (w0 + i < NL) {
            const uint2 v = *(const uint2*)(ybase + (size_t)i * ND);
            win[i][0] = __uint_as_float(v.x << 16);
            win[i][1] = __uint_as_float(v.x & 0xffff0000u);
            win[i][2] = __uint_as_float(v.y << 16);
            win[i][3] = __uint_as_float(v.y & 0xffff0000u);
        } else {
            win[i][0] = win[i][1] = win[i][2] = win[i][3] = 0.f;
        }
    }

#pragma unroll
    for (int w = 0; w < 4; ++w) {
        if (w0 + w < NW) {
            float* orow = Out + ((size_t)(b * NW + (w0 + w)) * FUTURE) * ND + eq;
#pragma unroll
            for (int f = 0; f < FUTURE; ++f) {
                const float btf = bt[f];                    // uniform -> SGPR
                float a0 = fmaf(btf, Sv.x, bsv.x);
                float a1 = fmaf(btf, Sv.y, bsv.y);
                float a2 = fmaf(btf, Sv.z, bsv.z);
                float a3 = fmaf(btf, Sv.w, bsv.w);
#pragma unroll
                for (int p = 0; p < PAST; ++p) {
                    const float c = Wt[f * PAST + p];       // uniform -> SGPR
                    a0 = fmaf(c, win[w + p][0], a0);
                    a1 = fmaf(c, win[w + p][1], a1);
                    a2 = fmaf(c, win[w + p][2], a2);
                    a3 = fmaf(c, win[w + p][3], a3);
                }
                *(float4*)(orow + (size_t)f * ND) = make_float4(a0, a1, a2, a3);
            }
        }
    }
}

// ---------------- launch ----------------
extern "C" void kernel_launch(void* const* d_in, const int* in_sizes, int n_in,
                              void* d_out, int out_size, void* d_ws, size_t ws_size,
                              hipStream_t stream) {
    const float* inp = (const float*)d_in[0];  // [64,256,512] fp32
    const float* Wt  = (const float*)d_in[1];  // [12,12]
    const float* bt  = (const float*)d_in[2];  // [12]
    const float* Ws  = (const float*)d_in[3];  // [512,512]
    const float* bs  = (const float*)d_in[4];  // [512]
    float* out = (float*)d_out;

    const size_t n_inp = (size_t)NB * NL * ND;            // 16,777,216
    ushort_t* Y     = (ushort_t*)d_ws;                               // 33.5 MB
    ushort_t* inp_b = (ushort_t*)((char*)d_ws + n_inp * 2);          // +33.5 MB
    ushort_t* Ws_b  = (ushort_t*)((char*)d_ws + n_inp * 4);          // +0.5 MB
    float*    S     = (float*)((char*)d_ws + n_inp * 4 + (size_t)ND * ND * 2);

    convert_inp<<<dim3(n_inp / 8 / 256), dim3(256), 0, stream>>>(inp, inp_b);
    prep_ws<<<dim3(ND), dim3(256), 0, stream>>>(Ws, Ws_b, S);
    gemm_spatial<<<dim3(ND / BN, (NB * NL) / BM), dim3(256), 0, stream>>>(inp_b, Ws_b, Y);
    temporal_kernel<<<dim3((NW + WTILE - 1) / WTILE, NB), dim3(256), 0, stream>>>(Y, Wt, bt, bs, S, out);
}